// Round 15
// baseline (18302.654 us; speedup 1.0000x reference)
//
#include <hip/hip_runtime.h>
#include <math.h>

// 2-layer GRU, T=4096, B=64, H=512, input=1. Output = final hidden (2,64,512) f32.
//
// R15 = R14 + per-wave flags + single barrier/step:
//  - flags[wg][ew] (ew = epilogue wave 0..3): each epilogue wave stores its h
//    slice, drains ITS OWN vmcnt, posts its sub-flag immediately (no WG-wide
//    barrier on the flag path; no tid0 centralization; no wait for slowest
//    wave). Consumers poll all 4 sub-flags of each producer (lane-parallel).
//  - red[2] parity double-buffer -> ONE __syncthreads per step (write red[t&1]
//    -> barrier -> epilogue reads; 2-buffer+1-barrier is race-free: reaching
//    iter t+2's write of red[p] requires passing barrier t+1, which requires
//    all waves to have read red[p] at iter t).
//  - overwrite guards poll sub-flag 0 only (wave0 past barrier v => all waves'
//    iter-v ring reads consumed).
// Kept from R14 (proven): 256 WGs (layer, jt, bq) x 512 thr; bf16-split MFMA;
// A-frags in VGPRs; relaxed-agent-atomic rings depth 4; u64 ring pairs;
// decentralized producer waits + monotone caches; deferred guards; 17-pad LDS.
// Flag algebra (id = layer*128 + jt*4 + bq; L0 posts t+1 after iter t; L1
// posts t after iter t, which computes state t-1):
//   L0 wave w waits L0(4w+i, bq) >= t            (i=0..3, all 4 sub-flags)
//   L1 wave w<4 waits L0(8w+i, bq) >= t          (x-side)
//   L1 wave w>=4 waits L1(8(w-4)+i, bq) >= t-1   (h-side)
//   L0 guard (wave4): L0(*,bq) >= t-2 && L1(*,bq) >= t-3   (sub-flag 0)
//   L1 guard (wave4): L1(*,bq) >= t-3                      (sub-flag 0)
// ws: ring0[4][512*64]u32 | ring1[...] | flags[1024*32] | aw0 | aw1

#define TT 4096
#define BB 64
#define HH 512
#define NWG 256
#define NFLAG (NWG * 4)
#define PADU 32
#define HB32 (HH * BB)

typedef __attribute__((ext_vector_type(8))) short bf16x8;
typedef __attribute__((ext_vector_type(4))) float f32x4;
typedef unsigned long long ull;

#define MFMA16(a, b, c) __builtin_amdgcn_mfma_f32_16x16x32_bf16((a), (b), (c), 0, 0, 0)
#define RIDX(c) ((((c) >> 4) * 17) + ((c) & 15))

__device__ __forceinline__ float sigm(float v) { return 1.0f / (1.0f + expf(-v)); }

__device__ __forceinline__ unsigned aldu(const unsigned* p) {
    return __hip_atomic_load((unsigned*)p, __ATOMIC_RELAXED, __HIP_MEMORY_SCOPE_AGENT);
}
__device__ __forceinline__ void astu(unsigned* p, unsigned v) {
    __hip_atomic_store(p, v, __ATOMIC_RELAXED, __HIP_MEMORY_SCOPE_AGENT);
}
__device__ __forceinline__ ull ald64(const ull* p) {
    return __hip_atomic_load((ull*)p, __ATOMIC_RELAXED, __HIP_MEMORY_SCOPE_AGENT);
}
__device__ __forceinline__ unsigned short rneb(float f) {   // fp32 -> bf16 RNE
    unsigned u = __float_as_uint(f);
    return (unsigned short)((u + 0x7fffu + ((u >> 16) & 1u)) >> 16);
}
__device__ __forceinline__ float bfhi_f(unsigned p) { return __uint_as_float(p & 0xffff0000u); }
__device__ __forceinline__ float bflo_f(unsigned p) { return __uint_as_float(p << 16); }

union frag_u { unsigned u[4]; bf16x8 v; };
__device__ __forceinline__ bf16x8 mkfrag(unsigned a, unsigned b, unsigned c, unsigned d) {
    frag_u x; x.u[0] = a; x.u[1] = b; x.u[2] = c; x.u[3] = d; return x.v;
}
__device__ __forceinline__ void wait_fence() {
    __builtin_amdgcn_sched_barrier(0);
    asm volatile("" ::: "memory");
}

__global__ __launch_bounds__(256) void zero_k(unsigned* p, int n) {
    int i = blockIdx.x * 256 + threadIdx.x;
    if (i < n) p[i] = 0u;
}

// A-frag prep (R9-R14 layout, verified): frag fb = ((rt*KTN + kt)*2 + split)*64 + lane,
// rt = gate*32 + jt; row = jt*16 + (lane&15); k = kt*32 + (lane>>4)*8 + i.
__global__ __launch_bounds__(256) void prep_aw0(const float* __restrict__ whh0,
                                                unsigned short* __restrict__ aw0) {
    int gid = blockIdx.x * 256 + threadIdx.x;           // 96*16*2*64
    if (gid >= 96 * 16 * 2 * 64) return;
    int lane = gid & 63, split = (gid >> 6) & 1, kt = (gid >> 7) & 15, rt = gid >> 11;
    int grow = (rt >> 5) * 512 + (rt & 31) * 16 + (lane & 15);
    int k0 = kt * 32 + (lane >> 4) * 8;
    #pragma unroll
    for (int i = 0; i < 8; ++i) {
        float val = whh0[(size_t)grow * 512 + k0 + i];
        unsigned short hb = rneb(val);
        unsigned short us = hb;
        if (split) us = rneb(val - __uint_as_float(((unsigned)hb) << 16));
        aw0[(size_t)gid * 8 + i] = us;
    }
}

__global__ __launch_bounds__(256) void prep_aw1(const float* __restrict__ wih1,
                                                const float* __restrict__ whh1,
                                                unsigned short* __restrict__ aw1) {
    int gid = blockIdx.x * 256 + threadIdx.x;           // 96*32*2*64
    if (gid >= 96 * 32 * 2 * 64) return;
    int lane = gid & 63, split = (gid >> 6) & 1, kt = (gid >> 7) & 31, rt = gid >> 12;
    int grow = (rt >> 5) * 512 + (rt & 31) * 16 + (lane & 15);
    #pragma unroll
    for (int i = 0; i < 8; ++i) {
        int k = kt * 32 + (lane >> 4) * 8 + i;
        float val = (k < 512) ? wih1[(size_t)grow * 512 + k]
                              : whh1[(size_t)grow * 512 + (k - 512)];
        unsigned short hb = rneb(val);
        unsigned short us = hb;
        if (split) us = rneb(val - __uint_as_float(((unsigned)hb) << 16));
        aw1[(size_t)gid * 8 + i] = us;
    }
}

// issue one kt's B loads (16 cols): buf[i] = pair (k0+2i, k0+2i+1), col bcol0
#define ISSUE_KT(buf, src64, ktr)                                               \
    {                                                                           \
        _Pragma("unroll")                                                       \
        for (int i = 0; i < 4; ++i)                                             \
            buf[i] = ald64((src64) + ((ktr) * 16 + (l >> 4) * 4 + i) * 64       \
                           + bcol0);                                            \
    }

#define COMPUTE_KT(buf, kk)                                                     \
    {                                                                           \
        unsigned p0 = (unsigned)buf[0], p1 = (unsigned)(buf[0] >> 32);          \
        unsigned p2 = (unsigned)buf[1], p3 = (unsigned)(buf[1] >> 32);          \
        unsigned p4 = (unsigned)buf[2], p5 = (unsigned)(buf[2] >> 32);          \
        unsigned p6 = (unsigned)buf[3], p7 = (unsigned)(buf[3] >> 32);          \
        bf16x8 Bh = mkfrag(__builtin_amdgcn_perm(p1, p0, 0x07060302u),          \
                           __builtin_amdgcn_perm(p3, p2, 0x07060302u),          \
                           __builtin_amdgcn_perm(p5, p4, 0x07060302u),          \
                           __builtin_amdgcn_perm(p7, p6, 0x07060302u));         \
        bf16x8 Bl = mkfrag(__builtin_amdgcn_perm(p1, p0, 0x05040100u),          \
                           __builtin_amdgcn_perm(p3, p2, 0x05040100u),          \
                           __builtin_amdgcn_perm(p5, p4, 0x05040100u),          \
                           __builtin_amdgcn_perm(p7, p6, 0x05040100u));         \
        _Pragma("unroll")                                                       \
        for (int g = 0; g < 3; ++g) {                                           \
            acc[g] = MFMA16(wA[kk][g][0], Bh, acc[g]);                          \
            acc[g] = MFMA16(wA[kk][g][0], Bl, acc[g]);                          \
            acc[g] = MFMA16(wA[kk][g][1], Bh, acc[g]);                          \
        }                                                                       \
    }

__global__ __launch_bounds__(512, 1) void gru_persist(
    const float* __restrict__ x,
    const float* __restrict__ wih0,
    const float* __restrict__ bih0, const float* __restrict__ bhh0,
    const float* __restrict__ bih1, const float* __restrict__ bhh1,
    unsigned* __restrict__ ws)
{
    __shared__ float red[2][8][3][272];       // 51 KB, parity double-buffer

    unsigned* r0 = ws;                        // [4][HB32] packed u32, idx=((k>>1)*64+b)*2+(k&1)
    unsigned* r1 = ws + 4 * HB32;
    unsigned* flags = ws + 8 * HB32;          // [256 wg][4 subwave] * PADU
    const bf16x8* aw0f = (const bf16x8*)(ws + 8 * HB32 + NFLAG * PADU);
    const bf16x8* aw1f = aw0f + (size_t)96 * 16 * 2 * 64;

    const int tid = threadIdx.x;
    const int l   = tid & 63;
    const int w   = tid >> 6;                 // wave 0..7 = k-slice
    const int id  = blockIdx.x;               // 0..255
    const int layer = id >> 7;
    const int jt  = (id >> 2) & 31;
    const int bq  = id & 3;                   // batch quarter
    const int bcol0 = bq * 16 + (l & 15);     // batch col for B loads

    // epilogue mapping (tid < 256): output (jl_e, b_e)
    const int jl_e = tid >> 4;                // 0..15 (valid when tid<256)
    const int ce   = tid & 15;
    const int b_e  = bq * 16 + ce;
    const int rg_e = jl_e & 3;
    const int l_r  = ((jl_e >> 2) << 4) | ce; // lane that held this (row,col)
    const int c_e  = RIDX(l_r * 4 + rg_e);
    const int jj   = jt * 16 + jl_e;
    const int hidx = ((jj >> 1) * 64 + b_e) * 2 + (jj & 1);   // packed h element

    unsigned fprod = 0, fguard = 0;           // per-lane monotone flag caches

    if (layer == 0) {
        // ===================== Layer 0 (K=512; wave w: kt = 2w, 2w+1) ==========
        bf16x8 wA[2][3][2];
        #pragma unroll
        for (int kk = 0; kk < 2; ++kk)
            #pragma unroll
            for (int g = 0; g < 3; ++g)
                #pragma unroll
                for (int s = 0; s < 2; ++s)
                    wA[kk][g][s] = aw0f[(size_t)(((g * 32 + jt) * 16 + (2 * w + kk)) * 2 + s) * 64 + l];

        const float wir = wih0[jj], wiz = wih0[512 + jj], win = wih0[1024 + jj];
        const float br  = bih0[jj] + bhh0[jj];
        const float bz  = bih0[512 + jj] + bhh0[512 + jj];
        const float bnx = bih0[1024 + jj], bnh = bhh0[1024 + jj];

        for (int t = 0; t < TT; ++t) {
            const unsigned* hin  = r0 + ((t + 3) & 3) * HB32;  // state t-1
            unsigned*       hout = r0 + (t & 3) * HB32;        // state t
            const ull* hin64 = (const ull*)hin;
            float (*redc)[3][272] = red[t & 1];

            unsigned po = aldu(hin + hidx);                    // self rows: no wait
            const float xv = x[(size_t)t * BB + b_e];

            // producer wait: 4 producers x 4 sub-flags, lanes 0-15
            if (l < 16) {
                const unsigned need = (unsigned)t;
                const int fidx = (((4 * w + (l >> 2)) * 4 + bq) * 4 + (l & 3)) * PADU;
                while (fprod < need) {
                    fprod = aldu(&flags[fidx]);
                    if (fprod < need) __builtin_amdgcn_s_sleep(1);
                }
            }
            wait_fence();

            f32x4 acc[3];
            #pragma unroll
            for (int g = 0; g < 3; ++g) acc[g] = (f32x4){0.f, 0.f, 0.f, 0.f};

            ull bbA[4], bbB[4];
            ISSUE_KT(bbA, hin64, 2 * w)
            ISSUE_KT(bbB, hin64, 2 * w + 1)
            COMPUTE_KT(bbA, 0)
            COMPUTE_KT(bbB, 1)

            // deferred overwrite guard (wave 4, sub-flag 0):
            // L0(*,bq)>=t-2 (lanes 0-31), L1(*,bq)>=t-3 (lanes 32-63)
            if (w == 4) {
                unsigned ng; int fidx;
                if (l < 32) { ng = (t >= 2) ? (unsigned)(t - 2) : 0u; fidx = (l * 4 + bq) * 4; }
                else        { ng = (t >= 3) ? (unsigned)(t - 3) : 0u; fidx = ((128 + (l - 32) * 4 + bq)) * 4; }
                while (fguard < ng) {
                    fguard = aldu(&flags[fidx * PADU]);
                    if (fguard < ng) __builtin_amdgcn_s_sleep(1);
                }
            }
            wait_fence();

            // reduce: every wave writes its partials into parity buffer
            #pragma unroll
            for (int g = 0; g < 3; ++g)
                *(f32x4*)&redc[w][g][RIDX(l * 4)] = acc[g];
            __syncthreads();                  // single barrier per step

            if (tid < 256) {
                float sr = 0.f, sz = 0.f, sn = 0.f;
                #pragma unroll
                for (int p = 0; p < 8; ++p) {
                    sr += redc[p][0][c_e];
                    sz += redc[p][1][c_e];
                    sn += redc[p][2][c_e];
                }
                float r = sigm(xv * wir + br + sr);
                float z = sigm(xv * wiz + bz + sz);
                float n = tanhf(xv * win + bnx + r * (sn + bnh));
                float hn = (1.0f - z) * n + z * (bfhi_f(po) + bflo_f(po));
                unsigned hb = rneb(hn);
                unsigned lb = rneb(hn - __uint_as_float(hb << 16));
                astu(hout + hidx, (hb << 16) | lb);
                asm volatile("s_waitcnt vmcnt(0)" ::: "memory");  // own wave's stores acked
                if (l == 0) astu(&flags[((id * 4) + w) * PADU], (unsigned)(t + 1));
            }
        }
    } else {
        // ===================== Layer 1 (K=1024; wave w: ktl = 4w..4w+3) ========
        bf16x8 wA[4][3][2];
        #pragma unroll
        for (int kk = 0; kk < 4; ++kk)
            #pragma unroll
            for (int g = 0; g < 3; ++g)
                #pragma unroll
                for (int s = 0; s < 2; ++s)
                    wA[kk][g][s] = aw1f[(size_t)(((g * 32 + jt) * 32 + (4 * w + kk)) * 2 + s) * 64 + l];

        const float br  = bih1[jj] + bhh1[jj];
        const float bz  = bih1[512 + jj] + bhh1[512 + jj];
        const float bnx = bih1[1024 + jj], bnh = bhh1[1024 + jj];
        const bool xside = (w < 4);

        for (int t = 1; t <= TT; ++t) {       // computes h1 state t-1
            const unsigned* y0  = r0 + ((t + 3) & 3) * HB32;   // h0 state t-1
            const unsigned* h1p = r1 + ((t + 2) & 3) * HB32;   // h1 state t-2
            unsigned*       h1o = r1 + ((t + 3) & 3) * HB32;   // h1 state t-1
            const ull* src64 = (const ull*)(xside ? y0 : h1p);
            const int kb = xside ? (4 * w) : (4 * (w - 4));    // ring kt base
            float (*redc)[3][272] = red[t & 1];

            unsigned po = aldu(h1p + hidx);                    // self rows

            // producer wait: 8 producers x 4 sub-flags, lanes 0-31
            if (l < 32) {
                unsigned need; int pidx;
                if (xside) { need = (unsigned)t;       pidx = (8 * w + (l >> 2)) * 4 + bq; }
                else       { need = (unsigned)(t - 1); pidx = 128 + (8 * (w - 4) + (l >> 2)) * 4 + bq; }
                const int fidx = (pidx * 4 + (l & 3)) * PADU;
                while (fprod < need) {
                    fprod = aldu(&flags[fidx]);
                    if (fprod < need) __builtin_amdgcn_s_sleep(1);
                }
            }
            wait_fence();

            f32x4 acc[3];
            #pragma unroll
            for (int g = 0; g < 3; ++g) acc[g] = (f32x4){0.f, 0.f, 0.f, 0.f};

            ull bb0[4], bb1[4], bb2[4], bb3[4];
            ISSUE_KT(bb0, src64, kb + 0)
            ISSUE_KT(bb1, src64, kb + 1)
            ISSUE_KT(bb2, src64, kb + 2)
            ISSUE_KT(bb3, src64, kb + 3)
            COMPUTE_KT(bb0, 0)
            COMPUTE_KT(bb1, 1)
            COMPUTE_KT(bb2, 2)
            COMPUTE_KT(bb3, 3)

            // deferred overwrite guard (wave 4, sub-flag 0): L1(*,bq) >= t-3
            if (w == 4 && l < 32) {
                const unsigned ng = (t >= 3) ? (unsigned)(t - 3) : 0u;
                const int fidx = ((128 + l * 4 + bq) * 4) * PADU;
                while (fguard < ng) {
                    fguard = aldu(&flags[fidx]);
                    if (fguard < ng) __builtin_amdgcn_s_sleep(1);
                }
            }
            wait_fence();

            // reduce: waves 0-3 partials feed r,z,nx; waves 4-7 r,z,nh
            #pragma unroll
            for (int g = 0; g < 3; ++g)
                *(f32x4*)&redc[w][g][RIDX(l * 4)] = acc[g];
            __syncthreads();                  // single barrier per step

            if (tid < 256) {
                float sr = 0.f, sz = 0.f, sx = 0.f, sh = 0.f;
                #pragma unroll
                for (int p = 0; p < 4; ++p) {
                    sr += redc[p][0][c_e];
                    sz += redc[p][1][c_e];
                    sx += redc[p][2][c_e];
                }
                #pragma unroll
                for (int p = 4; p < 8; ++p) {
                    sr += redc[p][0][c_e];
                    sz += redc[p][1][c_e];
                    sh += redc[p][2][c_e];
                }
                float r = sigm(sr + br);
                float z = sigm(sz + bz);
                float n = tanhf(sx + bnx + r * (sh + bnh));
                float hn = (1.0f - z) * n + z * (bfhi_f(po) + bflo_f(po));
                unsigned hb = rneb(hn);
                unsigned lb = rneb(hn - __uint_as_float(hb << 16));
                astu(h1o + hidx, (hb << 16) | lb);
                asm volatile("s_waitcnt vmcnt(0)" ::: "memory");
                if (l == 0) astu(&flags[((id * 4) + w) * PADU], (unsigned)t);
            }
        }
    }
}

// out[lyr][b][j] = f32(ring_lyr[slot3][...]) ; idx = ((j>>1)*64+b)*2+(j&1)
__global__ __launch_bounds__(256) void copy_out_k(const unsigned* __restrict__ ws,
                                                  float* __restrict__ out) {
    int i = blockIdx.x * 256 + threadIdx.x;   // 2*64*512
    int lyr = i >> 15;
    int rem = i & 32767;
    int b = rem >> 9;
    int j = rem & 511;
    unsigned p = ws[(size_t)lyr * 4 * HB32 + 3 * HB32 + ((j >> 1) * 64 + b) * 2 + (j & 1)];
    out[i] = bfhi_f(p) + bflo_f(p);
}

extern "C" void kernel_launch(void* const* d_in, const int* in_sizes, int n_in,
                              void* d_out, int out_size, void* d_ws, size_t ws_size,
                              hipStream_t stream)
{
    const float* x    = (const float*)d_in[0];
    const float* wih0 = (const float*)d_in[1];
    const float* whh0 = (const float*)d_in[2];
    const float* bih0 = (const float*)d_in[3];
    const float* bhh0 = (const float*)d_in[4];
    const float* wih1 = (const float*)d_in[5];
    const float* whh1 = (const float*)d_in[6];
    const float* bih1 = (const float*)d_in[7];
    const float* bhh1 = (const float*)d_in[8];
    float* out = (float*)d_out;
    unsigned* ws = (unsigned*)d_ws;

    unsigned short* aw0 = (unsigned short*)(ws + 8 * HB32 + NFLAG * PADU);
    unsigned short* aw1 = aw0 + (size_t)96 * 16 * 2 * 64 * 8;

    const int nzero = 8 * HB32 + NFLAG * PADU;
    zero_k<<<(nzero + 255) / 256, 256, 0, stream>>>(ws, nzero);
    prep_aw0<<<(96 * 16 * 2 * 64) / 256, 256, 0, stream>>>(whh0, aw0);
    prep_aw1<<<(96 * 32 * 2 * 64) / 256, 256, 0, stream>>>(wih1, whh1, aw1);
    gru_persist<<<NWG, 512, 0, stream>>>(x, wih0, bih0, bhh0, bih1, bhh1, ws);
    copy_out_k<<<(2 * BB * HH) / 256, 256, 0, stream>>>(ws, out);
}

// Round 16
// 11039.964 us; speedup vs baseline: 1.6579x; 1.6579x over previous
//
#include <hip/hip_runtime.h>
#include <math.h>

// 2-layer GRU, T=4096, B=64, H=512, input=1. Output = final hidden (2,64,512) f32.
//
// R16 = R14 (proven 10.0ms; R13/R15 sync restructures both regressed) + tail
// shave:
//  - hot-spin producer polls (no s_sleep; 4-8 lanes, poll throttled by its own
//    ~1200cy LLC load latency anyway)
//  - paired u64 epilogue stores: 128 threads x 2 adjacent rows (one ring
//    k-pair, layout-native) -> halves store count + drain acks, 8B contiguous
// Kept (R14 exact): 256 WGs (layer, jt, bq) x 512 thr; bf16-split MFMA
// (Ah*Bh+Ah*Bl+Al*Bh, fp32 acc); A-frags resident in VGPRs; relaxed-agent-
// atomic rings depth 4; u64 ring pairs; decentralized producer waits +
// monotone caches; deferred overwrite guards (wave4, s_sleep kept); two
// barriers/step; single flag/WG posted by tid0; 17-pad LDS reduce.
// Flag algebra (id = layer*128 + jt*4 + bq; L0 posts t+1 after iter t; L1
// posts t after iter t, which computes state t-1):
//   L0 wave w waits L0(4w+i, bq) >= t            (i=0..3)
//   L1 wave w<4 waits L0(8w+i, bq) >= t          (x-side, i=0..7)
//   L1 wave w>=4 waits L1(8(w-4)+i, bq) >= t-1   (h-side)
//   L0 guard (wave4): L0(*,bq) >= t-2 && L1(*,bq) >= t-3
//   L1 guard (wave4): L1(*,bq) >= t-3
// ws: ring0[4][512*64]u32 | ring1[...] | flags[256*32] | aw0 | aw1

#define TT 4096
#define BB 64
#define HH 512
#define NWG 256
#define PADU 32
#define HB32 (HH * BB)

typedef __attribute__((ext_vector_type(8))) short bf16x8;
typedef __attribute__((ext_vector_type(4))) float f32x4;
typedef unsigned long long ull;

#define MFMA16(a, b, c) __builtin_amdgcn_mfma_f32_16x16x32_bf16((a), (b), (c), 0, 0, 0)
#define RIDX(c) ((((c) >> 4) * 17) + ((c) & 15))

__device__ __forceinline__ float sigm(float v) { return 1.0f / (1.0f + expf(-v)); }

__device__ __forceinline__ unsigned aldu(const unsigned* p) {
    return __hip_atomic_load((unsigned*)p, __ATOMIC_RELAXED, __HIP_MEMORY_SCOPE_AGENT);
}
__device__ __forceinline__ void astu(unsigned* p, unsigned v) {
    __hip_atomic_store(p, v, __ATOMIC_RELAXED, __HIP_MEMORY_SCOPE_AGENT);
}
__device__ __forceinline__ ull ald64(const ull* p) {
    return __hip_atomic_load((ull*)p, __ATOMIC_RELAXED, __HIP_MEMORY_SCOPE_AGENT);
}
__device__ __forceinline__ void ast64(ull* p, ull v) {
    __hip_atomic_store(p, v, __ATOMIC_RELAXED, __HIP_MEMORY_SCOPE_AGENT);
}
__device__ __forceinline__ unsigned short rneb(float f) {   // fp32 -> bf16 RNE
    unsigned u = __float_as_uint(f);
    return (unsigned short)((u + 0x7fffu + ((u >> 16) & 1u)) >> 16);
}
__device__ __forceinline__ float bfhi_f(unsigned p) { return __uint_as_float(p & 0xffff0000u); }
__device__ __forceinline__ float bflo_f(unsigned p) { return __uint_as_float(p << 16); }

union frag_u { unsigned u[4]; bf16x8 v; };
__device__ __forceinline__ bf16x8 mkfrag(unsigned a, unsigned b, unsigned c, unsigned d) {
    frag_u x; x.u[0] = a; x.u[1] = b; x.u[2] = c; x.u[3] = d; return x.v;
}
__device__ __forceinline__ void wait_fence() {
    __builtin_amdgcn_sched_barrier(0);
    asm volatile("" ::: "memory");
}
__device__ __forceinline__ unsigned pack_h(float hn) {
    unsigned hb = rneb(hn);
    unsigned lb = rneb(hn - __uint_as_float(hb << 16));
    return (hb << 16) | lb;
}

__global__ __launch_bounds__(256) void zero_k(unsigned* p, int n) {
    int i = blockIdx.x * 256 + threadIdx.x;
    if (i < n) p[i] = 0u;
}

// A-frag prep (R9-R14 layout, verified): frag fb = ((rt*KTN + kt)*2 + split)*64 + lane,
// rt = gate*32 + jt; row = jt*16 + (lane&15); k = kt*32 + (lane>>4)*8 + i.
__global__ __launch_bounds__(256) void prep_aw0(const float* __restrict__ whh0,
                                                unsigned short* __restrict__ aw0) {
    int gid = blockIdx.x * 256 + threadIdx.x;           // 96*16*2*64
    if (gid >= 96 * 16 * 2 * 64) return;
    int lane = gid & 63, split = (gid >> 6) & 1, kt = (gid >> 7) & 15, rt = gid >> 11;
    int grow = (rt >> 5) * 512 + (rt & 31) * 16 + (lane & 15);
    int k0 = kt * 32 + (lane >> 4) * 8;
    #pragma unroll
    for (int i = 0; i < 8; ++i) {
        float val = whh0[(size_t)grow * 512 + k0 + i];
        unsigned short hb = rneb(val);
        unsigned short us = hb;
        if (split) us = rneb(val - __uint_as_float(((unsigned)hb) << 16));
        aw0[(size_t)gid * 8 + i] = us;
    }
}

__global__ __launch_bounds__(256) void prep_aw1(const float* __restrict__ wih1,
                                                const float* __restrict__ whh1,
                                                unsigned short* __restrict__ aw1) {
    int gid = blockIdx.x * 256 + threadIdx.x;           // 96*32*2*64
    if (gid >= 96 * 32 * 2 * 64) return;
    int lane = gid & 63, split = (gid >> 6) & 1, kt = (gid >> 7) & 31, rt = gid >> 12;
    int grow = (rt >> 5) * 512 + (rt & 31) * 16 + (lane & 15);
    #pragma unroll
    for (int i = 0; i < 8; ++i) {
        int k = kt * 32 + (lane >> 4) * 8 + i;
        float val = (k < 512) ? wih1[(size_t)grow * 512 + k]
                              : whh1[(size_t)grow * 512 + (k - 512)];
        unsigned short hb = rneb(val);
        unsigned short us = hb;
        if (split) us = rneb(val - __uint_as_float(((unsigned)hb) << 16));
        aw1[(size_t)gid * 8 + i] = us;
    }
}

// issue one kt's B loads (16 cols): buf[i] = pair (k0+2i, k0+2i+1), col bcol0
#define ISSUE_KT(buf, src64, ktr)                                               \
    {                                                                           \
        _Pragma("unroll")                                                       \
        for (int i = 0; i < 4; ++i)                                             \
            buf[i] = ald64((src64) + ((ktr) * 16 + (l >> 4) * 4 + i) * 64       \
                           + bcol0);                                            \
    }

#define COMPUTE_KT(buf, kk)                                                     \
    {                                                                           \
        unsigned p0 = (unsigned)buf[0], p1 = (unsigned)(buf[0] >> 32);          \
        unsigned p2 = (unsigned)buf[1], p3 = (unsigned)(buf[1] >> 32);          \
        unsigned p4 = (unsigned)buf[2], p5 = (unsigned)(buf[2] >> 32);          \
        unsigned p6 = (unsigned)buf[3], p7 = (unsigned)(buf[3] >> 32);          \
        bf16x8 Bh = mkfrag(__builtin_amdgcn_perm(p1, p0, 0x07060302u),          \
                           __builtin_amdgcn_perm(p3, p2, 0x07060302u),          \
                           __builtin_amdgcn_perm(p5, p4, 0x07060302u),          \
                           __builtin_amdgcn_perm(p7, p6, 0x07060302u));         \
        bf16x8 Bl = mkfrag(__builtin_amdgcn_perm(p1, p0, 0x05040100u),          \
                           __builtin_amdgcn_perm(p3, p2, 0x05040100u),          \
                           __builtin_amdgcn_perm(p5, p4, 0x05040100u),          \
                           __builtin_amdgcn_perm(p7, p6, 0x05040100u));         \
        _Pragma("unroll")                                                       \
        for (int g = 0; g < 3; ++g) {                                           \
            acc[g] = MFMA16(wA[kk][g][0], Bh, acc[g]);                          \
            acc[g] = MFMA16(wA[kk][g][0], Bl, acc[g]);                          \
            acc[g] = MFMA16(wA[kk][g][1], Bh, acc[g]);                          \
        }                                                                       \
    }

__global__ __launch_bounds__(512, 1) void gru_persist(
    const float* __restrict__ x,
    const float* __restrict__ wih0,
    const float* __restrict__ bih0, const float* __restrict__ bhh0,
    const float* __restrict__ bih1, const float* __restrict__ bhh1,
    unsigned* __restrict__ ws)
{
    __shared__ float red[8][3][272];          // 25.5 KB, 16->17 padded rows

    unsigned* r0 = ws;                        // [4][HB32] packed u32, idx=((k>>1)*64+b)*2+(k&1)
    unsigned* r1 = ws + 4 * HB32;
    unsigned* flags = ws + 8 * HB32;
    const bf16x8* aw0f = (const bf16x8*)(ws + 8 * HB32 + NWG * PADU);
    const bf16x8* aw1f = aw0f + (size_t)96 * 16 * 2 * 64;

    const int tid = threadIdx.x;
    const int l   = tid & 63;
    const int w   = tid >> 6;                 // wave 0..7 = k-slice
    const int id  = blockIdx.x;               // 0..255
    const int layer = id >> 7;
    const int jt  = (id >> 2) & 31;
    const int bq  = id & 3;                   // batch quarter
    const int bcol0 = bq * 16 + (l & 15);     // batch col for B loads

    // epilogue mapping (tid < 128): rows 2q, 2q+1 for batch col b_e
    const int q    = tid >> 4;                // 0..7 (valid when tid<128)
    const int ce   = tid & 15;
    const int b_e  = bq * 16 + ce;
    const int jlA  = 2 * q;                   // even local row
    const int rgA  = jlA & 3;                 // rgB = rgA+1 (same 16-chunk)
    const int l_r  = ((jlA >> 2) << 4) | ce;  // lane that held this (rowgrp,col)
    const int cA   = RIDX(l_r * 4 + rgA);
    const int cB   = cA + 1;
    const int jjA  = jt * 16 + jlA;
    const int jjB  = jjA + 1;
    const int pidx = (jt * 8 + q) * 64 + b_e; // u64 ring-pair index (rows jjA,jjB)

    unsigned fprod = 0, fguard = 0;           // per-lane monotone flag caches

    if (layer == 0) {
        // ===================== Layer 0 (K=512; wave w: kt = 2w, 2w+1) ==========
        bf16x8 wA[2][3][2];
        #pragma unroll
        for (int kk = 0; kk < 2; ++kk)
            #pragma unroll
            for (int g = 0; g < 3; ++g)
                #pragma unroll
                for (int s = 0; s < 2; ++s)
                    wA[kk][g][s] = aw0f[(size_t)(((g * 32 + jt) * 16 + (2 * w + kk)) * 2 + s) * 64 + l];

        const float wirA = wih0[jjA], wizA = wih0[512 + jjA], winA = wih0[1024 + jjA];
        const float wirB = wih0[jjB], wizB = wih0[512 + jjB], winB = wih0[1024 + jjB];
        const float brA = bih0[jjA] + bhh0[jjA];
        const float bzA = bih0[512 + jjA] + bhh0[512 + jjA];
        const float bnxA = bih0[1024 + jjA], bnhA = bhh0[1024 + jjA];
        const float brB = bih0[jjB] + bhh0[jjB];
        const float bzB = bih0[512 + jjB] + bhh0[512 + jjB];
        const float bnxB = bih0[1024 + jjB], bnhB = bhh0[1024 + jjB];

        for (int t = 0; t < TT; ++t) {
            const unsigned* hin  = r0 + ((t + 3) & 3) * HB32;  // state t-1
            unsigned*       hout = r0 + (t & 3) * HB32;        // state t
            const ull* hin64 = (const ull*)hin;

            ull po = ald64(hin64 + pidx);                      // self rows: no wait
            const float xv = x[(size_t)t * BB + b_e];

            if (l < 4) {                                       // producers: L0(4w+l, bq) >= t
                const unsigned need = (unsigned)t;
                while (fprod < need) fprod = aldu(&flags[((4 * w + l) * 4 + bq) * PADU]);
            }
            wait_fence();

            f32x4 acc[3];
            #pragma unroll
            for (int g = 0; g < 3; ++g) acc[g] = (f32x4){0.f, 0.f, 0.f, 0.f};

            ull bbA[4], bbB[4];
            ISSUE_KT(bbA, hin64, 2 * w)
            ISSUE_KT(bbB, hin64, 2 * w + 1)
            COMPUTE_KT(bbA, 0)
            COMPUTE_KT(bbB, 1)

            // deferred overwrite guard (wave 4): L0(*,bq)>=t-2, L1(*,bq)>=t-3
            if (w == 4) {
                unsigned ng; int fidx;
                if (l < 32) { ng = (t >= 2) ? (unsigned)(t - 2) : 0u; fidx = l * 4 + bq; }
                else        { ng = (t >= 3) ? (unsigned)(t - 3) : 0u; fidx = 128 + (l - 32) * 4 + bq; }
                while (fguard < ng) {
                    fguard = aldu(&flags[fidx * PADU]);
                    if (fguard < ng) __builtin_amdgcn_s_sleep(1);
                }
            }
            wait_fence();

            // single-round reduce: every wave writes its partials
            #pragma unroll
            for (int g = 0; g < 3; ++g)
                *(f32x4*)&red[w][g][RIDX(l * 4)] = acc[g];
            __syncthreads();

            if (tid < 128) {
                float srA = 0.f, szA = 0.f, snA = 0.f;
                float srB = 0.f, szB = 0.f, snB = 0.f;
                #pragma unroll
                for (int p = 0; p < 8; ++p) {
                    srA += red[p][0][cA]; szA += red[p][1][cA]; snA += red[p][2][cA];
                    srB += red[p][0][cB]; szB += red[p][1][cB]; snB += red[p][2][cB];
                }
                unsigned poA = (unsigned)po, poB = (unsigned)(po >> 32);
                float rA = sigm(xv * wirA + brA + srA);
                float zA = sigm(xv * wizA + bzA + szA);
                float nA = tanhf(xv * winA + bnxA + rA * (snA + bnhA));
                float hnA = (1.0f - zA) * nA + zA * (bfhi_f(poA) + bflo_f(poA));
                float rB = sigm(xv * wirB + brB + srB);
                float zB = sigm(xv * wizB + bzB + szB);
                float nB = tanhf(xv * winB + bnxB + rB * (snB + bnhB));
                float hnB = (1.0f - zB) * nB + zB * (bfhi_f(poB) + bflo_f(poB));
                ast64((ull*)hout + pidx, (ull)pack_h(hnA) | ((ull)pack_h(hnB) << 32));
            }
            __syncthreads();                  // all stores drained (barrier waits vmcnt)
            if (tid == 0) astu(&flags[id * PADU], (unsigned)(t + 1));
        }
    } else {
        // ===================== Layer 1 (K=1024; wave w: ktl = 4w..4w+3) ========
        bf16x8 wA[4][3][2];
        #pragma unroll
        for (int kk = 0; kk < 4; ++kk)
            #pragma unroll
            for (int g = 0; g < 3; ++g)
                #pragma unroll
                for (int s = 0; s < 2; ++s)
                    wA[kk][g][s] = aw1f[(size_t)(((g * 32 + jt) * 32 + (4 * w + kk)) * 2 + s) * 64 + l];

        const float brA = bih1[jjA] + bhh1[jjA];
        const float bzA = bih1[512 + jjA] + bhh1[512 + jjA];
        const float bnxA = bih1[1024 + jjA], bnhA = bhh1[1024 + jjA];
        const float brB = bih1[jjB] + bhh1[jjB];
        const float bzB = bih1[512 + jjB] + bhh1[512 + jjB];
        const float bnxB = bih1[1024 + jjB], bnhB = bhh1[1024 + jjB];
        const bool xside = (w < 4);

        for (int t = 1; t <= TT; ++t) {       // computes h1 state t-1
            const unsigned* y0  = r0 + ((t + 3) & 3) * HB32;   // h0 state t-1
            const unsigned* h1p = r1 + ((t + 2) & 3) * HB32;   // h1 state t-2
            unsigned*       h1o = r1 + ((t + 3) & 3) * HB32;   // h1 state t-1
            const ull* src64 = (const ull*)(xside ? y0 : h1p);
            const int kb = xside ? (4 * w) : (4 * (w - 4));    // ring kt base

            ull po = ald64((const ull*)h1p + pidx);            // self rows

            if (l < 8) {
                unsigned need; int fidx;
                if (xside) { need = (unsigned)t;       fidx = (8 * w + l) * 4 + bq; }
                else       { need = (unsigned)(t - 1); fidx = 128 + (8 * (w - 4) + l) * 4 + bq; }
                while (fprod < need) fprod = aldu(&flags[fidx * PADU]);
            }
            wait_fence();

            f32x4 acc[3];
            #pragma unroll
            for (int g = 0; g < 3; ++g) acc[g] = (f32x4){0.f, 0.f, 0.f, 0.f};

            ull bb0[4], bb1[4], bb2[4], bb3[4];
            ISSUE_KT(bb0, src64, kb + 0)
            ISSUE_KT(bb1, src64, kb + 1)
            ISSUE_KT(bb2, src64, kb + 2)
            ISSUE_KT(bb3, src64, kb + 3)
            COMPUTE_KT(bb0, 0)
            COMPUTE_KT(bb1, 1)
            COMPUTE_KT(bb2, 2)
            COMPUTE_KT(bb3, 3)

            // deferred overwrite guard (wave 4): L1(*,bq) >= t-3
            if (w == 4 && l < 32) {
                const unsigned ng = (t >= 3) ? (unsigned)(t - 3) : 0u;
                while (fguard < ng) {
                    fguard = aldu(&flags[(128 + l * 4 + bq) * PADU]);
                    if (fguard < ng) __builtin_amdgcn_s_sleep(1);
                }
            }
            wait_fence();

            // single-round reduce: waves 0-3 partials feed r,z,nx; waves 4-7 r,z,nh
            #pragma unroll
            for (int g = 0; g < 3; ++g)
                *(f32x4*)&red[w][g][RIDX(l * 4)] = acc[g];
            __syncthreads();

            if (tid < 128) {
                float srA = 0.f, szA = 0.f, sxA = 0.f, shA = 0.f;
                float srB = 0.f, szB = 0.f, sxB = 0.f, shB = 0.f;
                #pragma unroll
                for (int p = 0; p < 4; ++p) {
                    srA += red[p][0][cA]; szA += red[p][1][cA]; sxA += red[p][2][cA];
                    srB += red[p][0][cB]; szB += red[p][1][cB]; sxB += red[p][2][cB];
                }
                #pragma unroll
                for (int p = 4; p < 8; ++p) {
                    srA += red[p][0][cA]; szA += red[p][1][cA]; shA += red[p][2][cA];
                    srB += red[p][0][cB]; szB += red[p][1][cB]; shB += red[p][2][cB];
                }
                unsigned poA = (unsigned)po, poB = (unsigned)(po >> 32);
                float rA = sigm(srA + brA);
                float zA = sigm(szA + bzA);
                float nA = tanhf(sxA + bnxA + rA * (shA + bnhA));
                float hnA = (1.0f - zA) * nA + zA * (bfhi_f(poA) + bflo_f(poA));
                float rB = sigm(srB + brB);
                float zB = sigm(szB + bzB);
                float nB = tanhf(sxB + bnxB + rB * (shB + bnhB));
                float hnB = (1.0f - zB) * nB + zB * (bfhi_f(poB) + bflo_f(poB));
                ast64((ull*)h1o + pidx, (ull)pack_h(hnA) | ((ull)pack_h(hnB) << 32));
            }
            __syncthreads();
            if (tid == 0) astu(&flags[id * PADU], (unsigned)t);
        }
    }
}

// out[lyr][b][j] = f32(ring_lyr[slot3][...]) ; idx = ((j>>1)*64+b)*2+(j&1)
__global__ __launch_bounds__(256) void copy_out_k(const unsigned* __restrict__ ws,
                                                  float* __restrict__ out) {
    int i = blockIdx.x * 256 + threadIdx.x;   // 2*64*512
    int lyr = i >> 15;
    int rem = i & 32767;
    int b = rem >> 9;
    int j = rem & 511;
    unsigned p = ws[(size_t)lyr * 4 * HB32 + 3 * HB32 + ((j >> 1) * 64 + b) * 2 + (j & 1)];
    out[i] = bfhi_f(p) + bflo_f(p);
}

extern "C" void kernel_launch(void* const* d_in, const int* in_sizes, int n_in,
                              void* d_out, int out_size, void* d_ws, size_t ws_size,
                              hipStream_t stream)
{
    const float* x    = (const float*)d_in[0];
    const float* wih0 = (const float*)d_in[1];
    const float* whh0 = (const float*)d_in[2];
    const float* bih0 = (const float*)d_in[3];
    const float* bhh0 = (const float*)d_in[4];
    const float* wih1 = (const float*)d_in[5];
    const float* whh1 = (const float*)d_in[6];
    const float* bih1 = (const float*)d_in[7];
    const float* bhh1 = (const float*)d_in[8];
    float* out = (float*)d_out;
    unsigned* ws = (unsigned*)d_ws;

    unsigned short* aw0 = (unsigned short*)(ws + 8 * HB32 + NWG * PADU);
    unsigned short* aw1 = aw0 + (size_t)96 * 16 * 2 * 64 * 8;

    const int nzero = 8 * HB32 + NWG * PADU;
    zero_k<<<(nzero + 255) / 256, 256, 0, stream>>>(ws, nzero);
    prep_aw0<<<(96 * 16 * 2 * 64) / 256, 256, 0, stream>>>(whh0, aw0);
    prep_aw1<<<(96 * 32 * 2 * 64) / 256, 256, 0, stream>>>(wih1, whh1, aw1);
    gru_persist<<<NWG, 512, 0, stream>>>(x, wih0, bih0, bhh0, bih1, bhh1, ws);
    copy_out_k<<<(2 * BB * HH) / 256, 256, 0, stream>>>(ws, out);
}

// Round 17
// 10006.913 us; speedup vs baseline: 1.8290x; 1.1032x over previous
//
#include <hip/hip_runtime.h>
#include <math.h>

// 2-layer GRU, T=4096, B=64, H=512, input=1. Output = final hidden (2,64,512) f32.
//
// R17 = EXACT REVERT to R14 (measured 10.0ms; best). R13 (tag sync), R15
// (per-wave flags), R16 (hot-spin + paired stores) all regressed: the minimal
// 1-flag/WG + 2-barrier structure is the local optimum. Step period 2.44us =
// ~3 serial loaded-LLC hops (~1200cy each) + compute; latency-bound, not
// throughput-bound (HBM 2.9%, MfmaUtil 15%).
//  - 256 WGs = (layer, jt, batch-QUARTER bq); per-WG B-tile 16 cols; L1
//    issues all 4 kt load buffers in one LLC window.
//  - single-round LDS reduce: 8 waves write partials, ONE syncthreads,
//    epilogue sums 8 slots; red[8][3][272] (16->17 pad).
//  - bf16-split MFMA (Ah*Bh+Ah*Bl+Al*Bh, fp32 acc), A-frags resident in
//    VGPRs, relaxed-agent-atomic rings (depth 4) + per-WG flags + monotone
//    caches, decentralized producer waits (s_sleep backoff), deferred
//    overwrite guards, prefetched hold/x, u64 ring pairs.
// Flag algebra (id = layer*128 + jt*4 + bq; L0 posts t+1 after iter t; L1
// posts t after iter t, which computes state t-1):
//   L0 wave w waits L0(4w+i, bq) >= t            (i=0..3)
//   L1 wave w<4 waits L0(8w+i, bq) >= t          (x-side, i=0..7)
//   L1 wave w>=4 waits L1(8(w-4)+i, bq) >= t-1   (h-side)
//   L0 guard (wave4): L0(*,bq) >= t-2 && L1(*,bq) >= t-3
//   L1 guard (wave4): L1(*,bq) >= t-3
// ws: ring0[4][512*64]u32 | ring1[...] | flags[256*32] | aw0 | aw1

#define TT 4096
#define BB 64
#define HH 512
#define NWG 256
#define PADU 32
#define HB32 (HH * BB)

typedef __attribute__((ext_vector_type(8))) short bf16x8;
typedef __attribute__((ext_vector_type(4))) float f32x4;
typedef unsigned long long ull;

#define MFMA16(a, b, c) __builtin_amdgcn_mfma_f32_16x16x32_bf16((a), (b), (c), 0, 0, 0)
#define RIDX(c) ((((c) >> 4) * 17) + ((c) & 15))

__device__ __forceinline__ float sigm(float v) { return 1.0f / (1.0f + expf(-v)); }

__device__ __forceinline__ unsigned aldu(const unsigned* p) {
    return __hip_atomic_load((unsigned*)p, __ATOMIC_RELAXED, __HIP_MEMORY_SCOPE_AGENT);
}
__device__ __forceinline__ void astu(unsigned* p, unsigned v) {
    __hip_atomic_store(p, v, __ATOMIC_RELAXED, __HIP_MEMORY_SCOPE_AGENT);
}
__device__ __forceinline__ ull ald64(const ull* p) {
    return __hip_atomic_load((ull*)p, __ATOMIC_RELAXED, __HIP_MEMORY_SCOPE_AGENT);
}
__device__ __forceinline__ unsigned short rneb(float f) {   // fp32 -> bf16 RNE
    unsigned u = __float_as_uint(f);
    return (unsigned short)((u + 0x7fffu + ((u >> 16) & 1u)) >> 16);
}
__device__ __forceinline__ float bfhi_f(unsigned p) { return __uint_as_float(p & 0xffff0000u); }
__device__ __forceinline__ float bflo_f(unsigned p) { return __uint_as_float(p << 16); }

union frag_u { unsigned u[4]; bf16x8 v; };
__device__ __forceinline__ bf16x8 mkfrag(unsigned a, unsigned b, unsigned c, unsigned d) {
    frag_u x; x.u[0] = a; x.u[1] = b; x.u[2] = c; x.u[3] = d; return x.v;
}
__device__ __forceinline__ void wait_fence() {
    __builtin_amdgcn_sched_barrier(0);
    asm volatile("" ::: "memory");
}

__global__ __launch_bounds__(256) void zero_k(unsigned* p, int n) {
    int i = blockIdx.x * 256 + threadIdx.x;
    if (i < n) p[i] = 0u;
}

// A-frag prep (R9-R14 layout, verified): frag fb = ((rt*KTN + kt)*2 + split)*64 + lane,
// rt = gate*32 + jt; row = jt*16 + (lane&15); k = kt*32 + (lane>>4)*8 + i.
__global__ __launch_bounds__(256) void prep_aw0(const float* __restrict__ whh0,
                                                unsigned short* __restrict__ aw0) {
    int gid = blockIdx.x * 256 + threadIdx.x;           // 96*16*2*64
    if (gid >= 96 * 16 * 2 * 64) return;
    int lane = gid & 63, split = (gid >> 6) & 1, kt = (gid >> 7) & 15, rt = gid >> 11;
    int grow = (rt >> 5) * 512 + (rt & 31) * 16 + (lane & 15);
    int k0 = kt * 32 + (lane >> 4) * 8;
    #pragma unroll
    for (int i = 0; i < 8; ++i) {
        float val = whh0[(size_t)grow * 512 + k0 + i];
        unsigned short hb = rneb(val);
        unsigned short us = hb;
        if (split) us = rneb(val - __uint_as_float(((unsigned)hb) << 16));
        aw0[(size_t)gid * 8 + i] = us;
    }
}

__global__ __launch_bounds__(256) void prep_aw1(const float* __restrict__ wih1,
                                                const float* __restrict__ whh1,
                                                unsigned short* __restrict__ aw1) {
    int gid = blockIdx.x * 256 + threadIdx.x;           // 96*32*2*64
    if (gid >= 96 * 32 * 2 * 64) return;
    int lane = gid & 63, split = (gid >> 6) & 1, kt = (gid >> 7) & 31, rt = gid >> 12;
    int grow = (rt >> 5) * 512 + (rt & 31) * 16 + (lane & 15);
    #pragma unroll
    for (int i = 0; i < 8; ++i) {
        int k = kt * 32 + (lane >> 4) * 8 + i;
        float val = (k < 512) ? wih1[(size_t)grow * 512 + k]
                              : whh1[(size_t)grow * 512 + (k - 512)];
        unsigned short hb = rneb(val);
        unsigned short us = hb;
        if (split) us = rneb(val - __uint_as_float(((unsigned)hb) << 16));
        aw1[(size_t)gid * 8 + i] = us;
    }
}

// issue one kt's B loads (16 cols): buf[i] = pair (k0+2i, k0+2i+1), col bcol0
#define ISSUE_KT(buf, src64, ktr)                                               \
    {                                                                           \
        _Pragma("unroll")                                                       \
        for (int i = 0; i < 4; ++i)                                             \
            buf[i] = ald64((src64) + ((ktr) * 16 + (l >> 4) * 4 + i) * 64       \
                           + bcol0);                                            \
    }

#define COMPUTE_KT(buf, kk)                                                     \
    {                                                                           \
        unsigned p0 = (unsigned)buf[0], p1 = (unsigned)(buf[0] >> 32);          \
        unsigned p2 = (unsigned)buf[1], p3 = (unsigned)(buf[1] >> 32);          \
        unsigned p4 = (unsigned)buf[2], p5 = (unsigned)(buf[2] >> 32);          \
        unsigned p6 = (unsigned)buf[3], p7 = (unsigned)(buf[3] >> 32);          \
        bf16x8 Bh = mkfrag(__builtin_amdgcn_perm(p1, p0, 0x07060302u),          \
                           __builtin_amdgcn_perm(p3, p2, 0x07060302u),          \
                           __builtin_amdgcn_perm(p5, p4, 0x07060302u),          \
                           __builtin_amdgcn_perm(p7, p6, 0x07060302u));         \
        bf16x8 Bl = mkfrag(__builtin_amdgcn_perm(p1, p0, 0x05040100u),          \
                           __builtin_amdgcn_perm(p3, p2, 0x05040100u),          \
                           __builtin_amdgcn_perm(p5, p4, 0x05040100u),          \
                           __builtin_amdgcn_perm(p7, p6, 0x05040100u));         \
        _Pragma("unroll")                                                       \
        for (int g = 0; g < 3; ++g) {                                           \
            acc[g] = MFMA16(wA[kk][g][0], Bh, acc[g]);                          \
            acc[g] = MFMA16(wA[kk][g][0], Bl, acc[g]);                          \
            acc[g] = MFMA16(wA[kk][g][1], Bh, acc[g]);                          \
        }                                                                       \
    }

__global__ __launch_bounds__(512, 1) void gru_persist(
    const float* __restrict__ x,
    const float* __restrict__ wih0,
    const float* __restrict__ bih0, const float* __restrict__ bhh0,
    const float* __restrict__ bih1, const float* __restrict__ bhh1,
    unsigned* __restrict__ ws)
{
    __shared__ float red[8][3][272];          // 25.5 KB, 16->17 padded rows

    unsigned* r0 = ws;                        // [4][HB32] packed u32, idx=((k>>1)*64+b)*2+(k&1)
    unsigned* r1 = ws + 4 * HB32;
    unsigned* flags = ws + 8 * HB32;
    const bf16x8* aw0f = (const bf16x8*)(ws + 8 * HB32 + NWG * PADU);
    const bf16x8* aw1f = aw0f + (size_t)96 * 16 * 2 * 64;

    const int tid = threadIdx.x;
    const int l   = tid & 63;
    const int w   = tid >> 6;                 // wave 0..7 = k-slice
    const int id  = blockIdx.x;               // 0..255
    const int layer = id >> 7;
    const int jt  = (id >> 2) & 31;
    const int bq  = id & 3;                   // batch quarter
    const int bcol0 = bq * 16 + (l & 15);     // batch col for B loads

    // epilogue mapping (tid < 256): output (jl_e, b_e)
    const int jl_e = tid >> 4;                // 0..15 (valid when tid<256)
    const int ce   = tid & 15;
    const int b_e  = bq * 16 + ce;
    const int rg_e = jl_e & 3;
    const int l_r  = ((jl_e >> 2) << 4) | ce; // lane that held this (row,col)
    const int c_e  = RIDX(l_r * 4 + rg_e);
    const int jj   = jt * 16 + jl_e;
    const int hidx = ((jj >> 1) * 64 + b_e) * 2 + (jj & 1);   // packed h element

    unsigned fprod = 0, fguard = 0;           // per-lane monotone flag caches

    if (layer == 0) {
        // ===================== Layer 0 (K=512; wave w: kt = 2w, 2w+1) ==========
        bf16x8 wA[2][3][2];
        #pragma unroll
        for (int kk = 0; kk < 2; ++kk)
            #pragma unroll
            for (int g = 0; g < 3; ++g)
                #pragma unroll
                for (int s = 0; s < 2; ++s)
                    wA[kk][g][s] = aw0f[(size_t)(((g * 32 + jt) * 16 + (2 * w + kk)) * 2 + s) * 64 + l];

        const float wir = wih0[jj], wiz = wih0[512 + jj], win = wih0[1024 + jj];
        const float br  = bih0[jj] + bhh0[jj];
        const float bz  = bih0[512 + jj] + bhh0[512 + jj];
        const float bnx = bih0[1024 + jj], bnh = bhh0[1024 + jj];

        for (int t = 0; t < TT; ++t) {
            const unsigned* hin  = r0 + ((t + 3) & 3) * HB32;  // state t-1
            unsigned*       hout = r0 + (t & 3) * HB32;        // state t
            const ull* hin64 = (const ull*)hin;

            unsigned po = aldu(hin + hidx);                    // self rows: no wait
            const float xv = x[(size_t)t * BB + b_e];

            if (l < 4) {                                       // producers: L0(4w+l, bq) >= t
                const unsigned need = (unsigned)t;
                while (fprod < need) {
                    fprod = aldu(&flags[((4 * w + l) * 4 + bq) * PADU]);
                    if (fprod < need) __builtin_amdgcn_s_sleep(1);
                }
            }
            wait_fence();

            f32x4 acc[3];
            #pragma unroll
            for (int g = 0; g < 3; ++g) acc[g] = (f32x4){0.f, 0.f, 0.f, 0.f};

            ull bbA[4], bbB[4];
            ISSUE_KT(bbA, hin64, 2 * w)
            ISSUE_KT(bbB, hin64, 2 * w + 1)
            COMPUTE_KT(bbA, 0)
            COMPUTE_KT(bbB, 1)

            // deferred overwrite guard (wave 4): L0(*,bq)>=t-2, L1(*,bq)>=t-3
            if (w == 4) {
                unsigned ng; int fidx;
                if (l < 32) { ng = (t >= 2) ? (unsigned)(t - 2) : 0u; fidx = l * 4 + bq; }
                else        { ng = (t >= 3) ? (unsigned)(t - 3) : 0u; fidx = 128 + (l - 32) * 4 + bq; }
                while (fguard < ng) {
                    fguard = aldu(&flags[fidx * PADU]);
                    if (fguard < ng) __builtin_amdgcn_s_sleep(1);
                }
            }
            wait_fence();

            // single-round reduce: every wave writes its partials
            #pragma unroll
            for (int g = 0; g < 3; ++g)
                *(f32x4*)&red[w][g][RIDX(l * 4)] = acc[g];
            __syncthreads();

            if (tid < 256) {
                float sr = 0.f, sz = 0.f, sn = 0.f;
                #pragma unroll
                for (int p = 0; p < 8; ++p) {
                    sr += red[p][0][c_e];
                    sz += red[p][1][c_e];
                    sn += red[p][2][c_e];
                }
                float r = sigm(xv * wir + br + sr);
                float z = sigm(xv * wiz + bz + sz);
                float n = tanhf(xv * win + bnx + r * (sn + bnh));
                float hn = (1.0f - z) * n + z * (bfhi_f(po) + bflo_f(po));
                unsigned hb = rneb(hn);
                unsigned lb = rneb(hn - __uint_as_float(hb << 16));
                astu(hout + hidx, (hb << 16) | lb);
            }
            __syncthreads();                  // all stores drained (barrier waits vmcnt)
            if (tid == 0) astu(&flags[id * PADU], (unsigned)(t + 1));
        }
    } else {
        // ===================== Layer 1 (K=1024; wave w: ktl = 4w..4w+3) ========
        bf16x8 wA[4][3][2];
        #pragma unroll
        for (int kk = 0; kk < 4; ++kk)
            #pragma unroll
            for (int g = 0; g < 3; ++g)
                #pragma unroll
                for (int s = 0; s < 2; ++s)
                    wA[kk][g][s] = aw1f[(size_t)(((g * 32 + jt) * 32 + (4 * w + kk)) * 2 + s) * 64 + l];

        const float br  = bih1[jj] + bhh1[jj];
        const float bz  = bih1[512 + jj] + bhh1[512 + jj];
        const float bnx = bih1[1024 + jj], bnh = bhh1[1024 + jj];
        const bool xside = (w < 4);

        for (int t = 1; t <= TT; ++t) {       // computes h1 state t-1
            const unsigned* y0  = r0 + ((t + 3) & 3) * HB32;   // h0 state t-1
            const unsigned* h1p = r1 + ((t + 2) & 3) * HB32;   // h1 state t-2
            unsigned*       h1o = r1 + ((t + 3) & 3) * HB32;   // h1 state t-1
            const ull* src64 = (const ull*)(xside ? y0 : h1p);
            const int kb = xside ? (4 * w) : (4 * (w - 4));    // ring kt base

            unsigned po = aldu(h1p + hidx);                    // self rows

            if (l < 8) {
                unsigned need; int fidx;
                if (xside) { need = (unsigned)t;       fidx = (8 * w + l) * 4 + bq; }
                else       { need = (unsigned)(t - 1); fidx = 128 + (8 * (w - 4) + l) * 4 + bq; }
                while (fprod < need) {
                    fprod = aldu(&flags[fidx * PADU]);
                    if (fprod < need) __builtin_amdgcn_s_sleep(1);
                }
            }
            wait_fence();

            f32x4 acc[3];
            #pragma unroll
            for (int g = 0; g < 3; ++g) acc[g] = (f32x4){0.f, 0.f, 0.f, 0.f};

            ull bb0[4], bb1[4], bb2[4], bb3[4];
            ISSUE_KT(bb0, src64, kb + 0)
            ISSUE_KT(bb1, src64, kb + 1)
            ISSUE_KT(bb2, src64, kb + 2)
            ISSUE_KT(bb3, src64, kb + 3)
            COMPUTE_KT(bb0, 0)
            COMPUTE_KT(bb1, 1)
            COMPUTE_KT(bb2, 2)
            COMPUTE_KT(bb3, 3)

            // deferred overwrite guard (wave 4): L1(*,bq) >= t-3
            if (w == 4 && l < 32) {
                const unsigned ng = (t >= 3) ? (unsigned)(t - 3) : 0u;
                while (fguard < ng) {
                    fguard = aldu(&flags[(128 + l * 4 + bq) * PADU]);
                    if (fguard < ng) __builtin_amdgcn_s_sleep(1);
                }
            }
            wait_fence();

            // single-round reduce: waves 0-3 partials feed r,z,nx; waves 4-7 r,z,nh
            #pragma unroll
            for (int g = 0; g < 3; ++g)
                *(f32x4*)&red[w][g][RIDX(l * 4)] = acc[g];
            __syncthreads();

            if (tid < 256) {
                float sr = 0.f, sz = 0.f, sx = 0.f, sh = 0.f;
                #pragma unroll
                for (int p = 0; p < 4; ++p) {
                    sr += red[p][0][c_e];
                    sz += red[p][1][c_e];
                    sx += red[p][2][c_e];
                }
                #pragma unroll
                for (int p = 4; p < 8; ++p) {
                    sr += red[p][0][c_e];
                    sz += red[p][1][c_e];
                    sh += red[p][2][c_e];
                }
                float r = sigm(sr + br);
                float z = sigm(sz + bz);
                float n = tanhf(sx + bnx + r * (sh + bnh));
                float hn = (1.0f - z) * n + z * (bfhi_f(po) + bflo_f(po));
                unsigned hb = rneb(hn);
                unsigned lb = rneb(hn - __uint_as_float(hb << 16));
                astu(h1o + hidx, (hb << 16) | lb);
            }
            __syncthreads();
            if (tid == 0) astu(&flags[id * PADU], (unsigned)t);
        }
    }
}

// out[lyr][b][j] = f32(ring_lyr[slot3][...]) ; idx = ((j>>1)*64+b)*2+(j&1)
__global__ __launch_bounds__(256) void copy_out_k(const unsigned* __restrict__ ws,
                                                  float* __restrict__ out) {
    int i = blockIdx.x * 256 + threadIdx.x;   // 2*64*512
    int lyr = i >> 15;
    int rem = i & 32767;
    int b = rem >> 9;
    int j = rem & 511;
    unsigned p = ws[(size_t)lyr * 4 * HB32 + 3 * HB32 + ((j >> 1) * 64 + b) * 2 + (j & 1)];
    out[i] = bfhi_f(p) + bflo_f(p);
}

extern "C" void kernel_launch(void* const* d_in, const int* in_sizes, int n_in,
                              void* d_out, int out_size, void* d_ws, size_t ws_size,
                              hipStream_t stream)
{
    const float* x    = (const float*)d_in[0];
    const float* wih0 = (const float*)d_in[1];
    const float* whh0 = (const float*)d_in[2];
    const float* bih0 = (const float*)d_in[3];
    const float* bhh0 = (const float*)d_in[4];
    const float* wih1 = (const float*)d_in[5];
    const float* whh1 = (const float*)d_in[6];
    const float* bih1 = (const float*)d_in[7];
    const float* bhh1 = (const float*)d_in[8];
    float* out = (float*)d_out;
    unsigned* ws = (unsigned*)d_ws;

    unsigned short* aw0 = (unsigned short*)(ws + 8 * HB32 + NWG * PADU);
    unsigned short* aw1 = aw0 + (size_t)96 * 16 * 2 * 64 * 8;

    const int nzero = 8 * HB32 + NWG * PADU;
    zero_k<<<(nzero + 255) / 256, 256, 0, stream>>>(ws, nzero);
    prep_aw0<<<(96 * 16 * 2 * 64) / 256, 256, 0, stream>>>(whh0, aw0);
    prep_aw1<<<(96 * 32 * 2 * 64) / 256, 256, 0, stream>>>(wih1, whh1, aw1);
    gru_persist<<<NWG, 512, 0, stream>>>(x, wih0, bih0, bhh0, bih1, bhh1, ws);
    copy_out_k<<<(2 * BB * HH) / 256, 256, 0, stream>>>(ws, out);
}

// Round 19
// 9963.824 us; speedup vs baseline: 1.8369x; 1.0043x over previous
//
#include <hip/hip_runtime.h>
#include <math.h>

// 2-layer GRU, T=4096, B=64, H=512, input=1. Output = final hidden (2,64,512) f32.
//
// R19 = R14/R17 (proven 10.0ms x2) + ONE change: hot-spin producer polls
// (no s_sleep in the critical producer-wait loops; guards keep backoff).
// Isolates R16's bundled variable: its regression is attributable to the
// paired-u64 epilogue (2 serial transcendental chains), not hot-spin.
// R18's XCD-local sc0 exchange HUNG (sc0 load L1-bypass unverifiable) and is
// abandoned; R13/R15 sync restructures regressed. R14 structure is final:
//  - 256 WGs = (layer, jt, batch-QUARTER bq) x 512 thr; per-WG B-tile 16 cols;
//    L1 issues all 4 kt load buffers in one LLC window.
//  - single-round LDS reduce (8 waves write, 1 barrier, epilogue sums 8 slots)
//  - bf16-split MFMA (Ah*Bh+Ah*Bl+Al*Bh, fp32 acc), A-frags resident in VGPRs,
//    relaxed-agent-atomic rings (depth 4) + per-WG flags + monotone caches,
//    deferred overwrite guards, prefetched hold/x, u64 ring pairs.
// Flag algebra (id = layer*128 + jt*4 + bq; L0 posts t+1 after iter t; L1
// posts t after iter t, which computes state t-1):
//   L0 wave w waits L0(4w+i, bq) >= t            (i=0..3)
//   L1 wave w<4 waits L0(8w+i, bq) >= t          (x-side, i=0..7)
//   L1 wave w>=4 waits L1(8(w-4)+i, bq) >= t-1   (h-side)
//   L0 guard (wave4): L0(*,bq) >= t-2 && L1(*,bq) >= t-3
//   L1 guard (wave4): L1(*,bq) >= t-3
// ws: ring0[4][512*64]u32 | ring1[...] | flags[256*32] | aw0 | aw1

#define TT 4096
#define BB 64
#define HH 512
#define NWG 256
#define PADU 32
#define HB32 (HH * BB)

typedef __attribute__((ext_vector_type(8))) short bf16x8;
typedef __attribute__((ext_vector_type(4))) float f32x4;
typedef unsigned long long ull;

#define MFMA16(a, b, c) __builtin_amdgcn_mfma_f32_16x16x32_bf16((a), (b), (c), 0, 0, 0)
#define RIDX(c) ((((c) >> 4) * 17) + ((c) & 15))

__device__ __forceinline__ float sigm(float v) { return 1.0f / (1.0f + expf(-v)); }

__device__ __forceinline__ unsigned aldu(const unsigned* p) {
    return __hip_atomic_load((unsigned*)p, __ATOMIC_RELAXED, __HIP_MEMORY_SCOPE_AGENT);
}
__device__ __forceinline__ void astu(unsigned* p, unsigned v) {
    __hip_atomic_store(p, v, __ATOMIC_RELAXED, __HIP_MEMORY_SCOPE_AGENT);
}
__device__ __forceinline__ ull ald64(const ull* p) {
    return __hip_atomic_load((ull*)p, __ATOMIC_RELAXED, __HIP_MEMORY_SCOPE_AGENT);
}
__device__ __forceinline__ unsigned short rneb(float f) {   // fp32 -> bf16 RNE
    unsigned u = __float_as_uint(f);
    return (unsigned short)((u + 0x7fffu + ((u >> 16) & 1u)) >> 16);
}
__device__ __forceinline__ float bfhi_f(unsigned p) { return __uint_as_float(p & 0xffff0000u); }
__device__ __forceinline__ float bflo_f(unsigned p) { return __uint_as_float(p << 16); }

union frag_u { unsigned u[4]; bf16x8 v; };
__device__ __forceinline__ bf16x8 mkfrag(unsigned a, unsigned b, unsigned c, unsigned d) {
    frag_u x; x.u[0] = a; x.u[1] = b; x.u[2] = c; x.u[3] = d; return x.v;
}
__device__ __forceinline__ void wait_fence() {
    __builtin_amdgcn_sched_barrier(0);
    asm volatile("" ::: "memory");
}

__global__ __launch_bounds__(256) void zero_k(unsigned* p, int n) {
    int i = blockIdx.x * 256 + threadIdx.x;
    if (i < n) p[i] = 0u;
}

// A-frag prep (R9-R17 layout, verified): frag fb = ((rt*KTN + kt)*2 + split)*64 + lane,
// rt = gate*32 + jt; row = jt*16 + (lane&15); k = kt*32 + (lane>>4)*8 + i.
__global__ __launch_bounds__(256) void prep_aw0(const float* __restrict__ whh0,
                                                unsigned short* __restrict__ aw0) {
    int gid = blockIdx.x * 256 + threadIdx.x;           // 96*16*2*64
    if (gid >= 96 * 16 * 2 * 64) return;
    int lane = gid & 63, split = (gid >> 6) & 1, kt = (gid >> 7) & 15, rt = gid >> 11;
    int grow = (rt >> 5) * 512 + (rt & 31) * 16 + (lane & 15);
    int k0 = kt * 32 + (lane >> 4) * 8;
    #pragma unroll
    for (int i = 0; i < 8; ++i) {
        float val = whh0[(size_t)grow * 512 + k0 + i];
        unsigned short hb = rneb(val);
        unsigned short us = hb;
        if (split) us = rneb(val - __uint_as_float(((unsigned)hb) << 16));
        aw0[(size_t)gid * 8 + i] = us;
    }
}

__global__ __launch_bounds__(256) void prep_aw1(const float* __restrict__ wih1,
                                                const float* __restrict__ whh1,
                                                unsigned short* __restrict__ aw1) {
    int gid = blockIdx.x * 256 + threadIdx.x;           // 96*32*2*64
    if (gid >= 96 * 32 * 2 * 64) return;
    int lane = gid & 63, split = (gid >> 6) & 1, kt = (gid >> 7) & 31, rt = gid >> 12;
    int grow = (rt >> 5) * 512 + (rt & 31) * 16 + (lane & 15);
    #pragma unroll
    for (int i = 0; i < 8; ++i) {
        int k = kt * 32 + (lane >> 4) * 8 + i;
        float val = (k < 512) ? wih1[(size_t)grow * 512 + k]
                              : whh1[(size_t)grow * 512 + (k - 512)];
        unsigned short hb = rneb(val);
        unsigned short us = hb;
        if (split) us = rneb(val - __uint_as_float(((unsigned)hb) << 16));
        aw1[(size_t)gid * 8 + i] = us;
    }
}

// issue one kt's B loads (16 cols): buf[i] = pair (k0+2i, k0+2i+1), col bcol0
#define ISSUE_KT(buf, src64, ktr)                                               \
    {                                                                           \
        _Pragma("unroll")                                                       \
        for (int i = 0; i < 4; ++i)                                             \
            buf[i] = ald64((src64) + ((ktr) * 16 + (l >> 4) * 4 + i) * 64       \
                           + bcol0);                                            \
    }

#define COMPUTE_KT(buf, kk)                                                     \
    {                                                                           \
        unsigned p0 = (unsigned)buf[0], p1 = (unsigned)(buf[0] >> 32);          \
        unsigned p2 = (unsigned)buf[1], p3 = (unsigned)(buf[1] >> 32);          \
        unsigned p4 = (unsigned)buf[2], p5 = (unsigned)(buf[2] >> 32);          \
        unsigned p6 = (unsigned)buf[3], p7 = (unsigned)(buf[3] >> 32);          \
        bf16x8 Bh = mkfrag(__builtin_amdgcn_perm(p1, p0, 0x07060302u),          \
                           __builtin_amdgcn_perm(p3, p2, 0x07060302u),          \
                           __builtin_amdgcn_perm(p5, p4, 0x07060302u),          \
                           __builtin_amdgcn_perm(p7, p6, 0x07060302u));         \
        bf16x8 Bl = mkfrag(__builtin_amdgcn_perm(p1, p0, 0x05040100u),          \
                           __builtin_amdgcn_perm(p3, p2, 0x05040100u),          \
                           __builtin_amdgcn_perm(p5, p4, 0x05040100u),          \
                           __builtin_amdgcn_perm(p7, p6, 0x05040100u));         \
        _Pragma("unroll")                                                       \
        for (int g = 0; g < 3; ++g) {                                           \
            acc[g] = MFMA16(wA[kk][g][0], Bh, acc[g]);                          \
            acc[g] = MFMA16(wA[kk][g][0], Bl, acc[g]);                          \
            acc[g] = MFMA16(wA[kk][g][1], Bh, acc[g]);                          \
        }                                                                       \
    }

__global__ __launch_bounds__(512, 1) void gru_persist(
    const float* __restrict__ x,
    const float* __restrict__ wih0,
    const float* __restrict__ bih0, const float* __restrict__ bhh0,
    const float* __restrict__ bih1, const float* __restrict__ bhh1,
    unsigned* __restrict__ ws)
{
    __shared__ float red[8][3][272];          // 25.5 KB, 16->17 padded rows

    unsigned* r0 = ws;                        // [4][HB32] packed u32, idx=((k>>1)*64+b)*2+(k&1)
    unsigned* r1 = ws + 4 * HB32;
    unsigned* flags = ws + 8 * HB32;
    const bf16x8* aw0f = (const bf16x8*)(ws + 8 * HB32 + NWG * PADU);
    const bf16x8* aw1f = aw0f + (size_t)96 * 16 * 2 * 64;

    const int tid = threadIdx.x;
    const int l   = tid & 63;
    const int w   = tid >> 6;                 // wave 0..7 = k-slice
    const int id  = blockIdx.x;               // 0..255
    const int layer = id >> 7;
    const int jt  = (id >> 2) & 31;
    const int bq  = id & 3;                   // batch quarter
    const int bcol0 = bq * 16 + (l & 15);     // batch col for B loads

    // epilogue mapping (tid < 256): output (jl_e, b_e)
    const int jl_e = tid >> 4;                // 0..15 (valid when tid<256)
    const int ce   = tid & 15;
    const int b_e  = bq * 16 + ce;
    const int rg_e = jl_e & 3;
    const int l_r  = ((jl_e >> 2) << 4) | ce; // lane that held this (row,col)
    const int c_e  = RIDX(l_r * 4 + rg_e);
    const int jj   = jt * 16 + jl_e;
    const int hidx = ((jj >> 1) * 64 + b_e) * 2 + (jj & 1);   // packed h element

    unsigned fprod = 0, fguard = 0;           // per-lane monotone flag caches

    if (layer == 0) {
        // ===================== Layer 0 (K=512; wave w: kt = 2w, 2w+1) ==========
        bf16x8 wA[2][3][2];
        #pragma unroll
        for (int kk = 0; kk < 2; ++kk)
            #pragma unroll
            for (int g = 0; g < 3; ++g)
                #pragma unroll
                for (int s = 0; s < 2; ++s)
                    wA[kk][g][s] = aw0f[(size_t)(((g * 32 + jt) * 16 + (2 * w + kk)) * 2 + s) * 64 + l];

        const float wir = wih0[jj], wiz = wih0[512 + jj], win = wih0[1024 + jj];
        const float br  = bih0[jj] + bhh0[jj];
        const float bz  = bih0[512 + jj] + bhh0[512 + jj];
        const float bnx = bih0[1024 + jj], bnh = bhh0[1024 + jj];

        for (int t = 0; t < TT; ++t) {
            const unsigned* hin  = r0 + ((t + 3) & 3) * HB32;  // state t-1
            unsigned*       hout = r0 + (t & 3) * HB32;        // state t
            const ull* hin64 = (const ull*)hin;

            unsigned po = aldu(hin + hidx);                    // self rows: no wait
            const float xv = x[(size_t)t * BB + b_e];

            if (l < 4) {                                       // producers: hot-spin
                const unsigned need = (unsigned)t;
                while (fprod < need)
                    fprod = aldu(&flags[((4 * w + l) * 4 + bq) * PADU]);
            }
            wait_fence();

            f32x4 acc[3];
            #pragma unroll
            for (int g = 0; g < 3; ++g) acc[g] = (f32x4){0.f, 0.f, 0.f, 0.f};

            ull bbA[4], bbB[4];
            ISSUE_KT(bbA, hin64, 2 * w)
            ISSUE_KT(bbB, hin64, 2 * w + 1)
            COMPUTE_KT(bbA, 0)
            COMPUTE_KT(bbB, 1)

            // deferred overwrite guard (wave 4): L0(*,bq)>=t-2, L1(*,bq)>=t-3
            if (w == 4) {
                unsigned ng; int fidx;
                if (l < 32) { ng = (t >= 2) ? (unsigned)(t - 2) : 0u; fidx = l * 4 + bq; }
                else        { ng = (t >= 3) ? (unsigned)(t - 3) : 0u; fidx = 128 + (l - 32) * 4 + bq; }
                while (fguard < ng) {
                    fguard = aldu(&flags[fidx * PADU]);
                    if (fguard < ng) __builtin_amdgcn_s_sleep(1);
                }
            }
            wait_fence();

            // single-round reduce: every wave writes its partials
            #pragma unroll
            for (int g = 0; g < 3; ++g)
                *(f32x4*)&red[w][g][RIDX(l * 4)] = acc[g];
            __syncthreads();

            if (tid < 256) {
                float sr = 0.f, sz = 0.f, sn = 0.f;
                #pragma unroll
                for (int p = 0; p < 8; ++p) {
                    sr += red[p][0][c_e];
                    sz += red[p][1][c_e];
                    sn += red[p][2][c_e];
                }
                float r = sigm(xv * wir + br + sr);
                float z = sigm(xv * wiz + bz + sz);
                float n = tanhf(xv * win + bnx + r * (sn + bnh));
                float hn = (1.0f - z) * n + z * (bfhi_f(po) + bflo_f(po));
                unsigned hb = rneb(hn);
                unsigned lb = rneb(hn - __uint_as_float(hb << 16));
                astu(hout + hidx, (hb << 16) | lb);
            }
            __syncthreads();                  // all stores drained (barrier waits vmcnt)
            if (tid == 0) astu(&flags[id * PADU], (unsigned)(t + 1));
        }
    } else {
        // ===================== Layer 1 (K=1024; wave w: ktl = 4w..4w+3) ========
        bf16x8 wA[4][3][2];
        #pragma unroll
        for (int kk = 0; kk < 4; ++kk)
            #pragma unroll
            for (int g = 0; g < 3; ++g)
                #pragma unroll
                for (int s = 0; s < 2; ++s)
                    wA[kk][g][s] = aw1f[(size_t)(((g * 32 + jt) * 32 + (4 * w + kk)) * 2 + s) * 64 + l];

        const float br  = bih1[jj] + bhh1[jj];
        const float bz  = bih1[512 + jj] + bhh1[512 + jj];
        const float bnx = bih1[1024 + jj], bnh = bhh1[1024 + jj];
        const bool xside = (w < 4);

        for (int t = 1; t <= TT; ++t) {       // computes h1 state t-1
            const unsigned* y0  = r0 + ((t + 3) & 3) * HB32;   // h0 state t-1
            const unsigned* h1p = r1 + ((t + 2) & 3) * HB32;   // h1 state t-2
            unsigned*       h1o = r1 + ((t + 3) & 3) * HB32;   // h1 state t-1
            const ull* src64 = (const ull*)(xside ? y0 : h1p);
            const int kb = xside ? (4 * w) : (4 * (w - 4));    // ring kt base

            unsigned po = aldu(h1p + hidx);                    // self rows

            if (l < 8) {                                       // producers: hot-spin
                unsigned need; int fidx;
                if (xside) { need = (unsigned)t;       fidx = (8 * w + l) * 4 + bq; }
                else       { need = (unsigned)(t - 1); fidx = 128 + (8 * (w - 4) + l) * 4 + bq; }
                while (fprod < need)
                    fprod = aldu(&flags[fidx * PADU]);
            }
            wait_fence();

            f32x4 acc[3];
            #pragma unroll
            for (int g = 0; g < 3; ++g) acc[g] = (f32x4){0.f, 0.f, 0.f, 0.f};

            ull bb0[4], bb1[4], bb2[4], bb3[4];
            ISSUE_KT(bb0, src64, kb + 0)
            ISSUE_KT(bb1, src64, kb + 1)
            ISSUE_KT(bb2, src64, kb + 2)
            ISSUE_KT(bb3, src64, kb + 3)
            COMPUTE_KT(bb0, 0)
            COMPUTE_KT(bb1, 1)
            COMPUTE_KT(bb2, 2)
            COMPUTE_KT(bb3, 3)

            // deferred overwrite guard (wave 4): L1(*,bq) >= t-3
            if (w == 4 && l < 32) {
                const unsigned ng = (t >= 3) ? (unsigned)(t - 3) : 0u;
                while (fguard < ng) {
                    fguard = aldu(&flags[(128 + l * 4 + bq) * PADU]);
                    if (fguard < ng) __builtin_amdgcn_s_sleep(1);
                }
            }
            wait_fence();

            // single-round reduce: waves 0-3 partials feed r,z,nx; waves 4-7 r,z,nh
            #pragma unroll
            for (int g = 0; g < 3; ++g)
                *(f32x4*)&red[w][g][RIDX(l * 4)] = acc[g];
            __syncthreads();

            if (tid < 256) {
                float sr = 0.f, sz = 0.f, sx = 0.f, sh = 0.f;
                #pragma unroll
                for (int p = 0; p < 4; ++p) {
                    sr += red[p][0][c_e];
                    sz += red[p][1][c_e];
                    sx += red[p][2][c_e];
                }
                #pragma unroll
                for (int p = 4; p < 8; ++p) {
                    sr += red[p][0][c_e];
                    sz += red[p][1][c_e];
                    sh += red[p][2][c_e];
                }
                float r = sigm(sr + br);
                float z = sigm(sz + bz);
                float n = tanhf(sx + bnx + r * (sh + bnh));
                float hn = (1.0f - z) * n + z * (bfhi_f(po) + bflo_f(po));
                unsigned hb = rneb(hn);
                unsigned lb = rneb(hn - __uint_as_float(hb << 16));
                astu(h1o + hidx, (hb << 16) | lb);
            }
            __syncthreads();
            if (tid == 0) astu(&flags[id * PADU], (unsigned)t);
        }
    }
}

// out[lyr][b][j] = f32(ring_lyr[slot3][...]) ; idx = ((j>>1)*64+b)*2+(j&1)
__global__ __launch_bounds__(256) void copy_out_k(const unsigned* __restrict__ ws,
                                                  float* __restrict__ out) {
    int i = blockIdx.x * 256 + threadIdx.x;   // 2*64*512
    int lyr = i >> 15;
    int rem = i & 32767;
    int b = rem >> 9;
    int j = rem & 511;
    unsigned p = ws[(size_t)lyr * 4 * HB32 + 3 * HB32 + ((j >> 1) * 64 + b) * 2 + (j & 1)];
    out[i] = bfhi_f(p) + bflo_f(p);
}

extern "C" void kernel_launch(void* const* d_in, const int* in_sizes, int n_in,
                              void* d_out, int out_size, void* d_ws, size_t ws_size,
                              hipStream_t stream)
{
    const float* x    = (const float*)d_in[0];
    const float* wih0 = (const float*)d_in[1];
    const float* whh0 = (const float*)d_in[2];
    const float* bih0 = (const float*)d_in[3];
    const float* bhh0 = (const float*)d_in[4];
    const float* wih1 = (const float*)d_in[5];
    const float* whh1 = (const float*)d_in[6];
    const float* bih1 = (const float*)d_in[7];
    const float* bhh1 = (const float*)d_in[8];
    float* out = (float*)d_out;
    unsigned* ws = (unsigned*)d_ws;

    unsigned short* aw0 = (unsigned short*)(ws + 8 * HB32 + NWG * PADU);
    unsigned short* aw1 = aw0 + (size_t)96 * 16 * 2 * 64 * 8;

    const int nzero = 8 * HB32 + NWG * PADU;
    zero_k<<<(nzero + 255) / 256, 256, 0, stream>>>(ws, nzero);
    prep_aw0<<<(96 * 16 * 2 * 64) / 256, 256, 0, stream>>>(whh0, aw0);
    prep_aw1<<<(96 * 32 * 2 * 64) / 256, 256, 0, stream>>>(wih1, whh1, aw1);
    gru_persist<<<NWG, 512, 0, stream>>>(x, wih0, bih0, bhh0, bih1, bhh1, ws);
    copy_out_k<<<(2 * BB * HH) / 256, 256, 0, stream>>>(ws, out);
}